// Round 14
// baseline (282.774 us; speedup 1.0000x reference)
//
#include <hip/hip_runtime.h>

#define NPTS 4096
#define NBATCH 4
#define HDIM 192
#define CDIM 384
#define FINF 3.4e38f

typedef _Float16 f16x8 __attribute__((ext_vector_type(8)));
typedef float f32x4 __attribute__((ext_vector_type(4)));
typedef unsigned long long u64;

// ---------------- K0: W2 [192][384] f32 -> fragment-major f16 chunks (R12, unchanged) --
__global__ __launch_bounds__(256) void prep_w2(const float* __restrict__ W2,
                                               _Float16* __restrict__ W2F) {
  const int j = blockIdx.x * 256 + threadIdx.x;   // 9216 chunks
  if (j < 9216) {
    const int lane = j & 63, r = lane & 15, kg = lane >> 4;
    const int kt = (j >> 6) % 6, ct = j / 384;
    const int c = ct * 16 + r, h0 = kt * 32 + kg * 8;
    f16x8 v;
#pragma unroll
    for (int e = 0; e < 8; ++e) v[e] = (_Float16)W2[(size_t)(h0 + e) * CDIM + c];
    *(f16x8*)(W2F + (size_t)j * 8) = v;
  }
}

// ---------------- K0b: per-batch bitonic sort by (x, idx) (R13, verified) --------------
__global__ __launch_bounds__(1024) void sort_kernel(const float* __restrict__ pts,
                                                    float4* __restrict__ sp4) {
  __shared__ float kx[4096];
  __shared__ int   ki[4096];
  const int b = blockIdx.x;
  const float* P = pts + (size_t)b * NPTS * 3;
  const int t = threadIdx.x;
  for (int i = t; i < 4096; i += 1024) { kx[i] = P[3 * i]; ki[i] = i; }
  __syncthreads();
  for (int k = 2; k <= 4096; k <<= 1) {
    for (int jj = k >> 1; jj > 0; jj >>= 1) {
      for (int m = t; m < 2048; m += 1024) {
        const int i = ((m & ~(jj - 1)) << 1) | (m & (jj - 1));
        const int p = i | jj;
        const bool up = (i & k) == 0;
        const float xi = kx[i], xp = kx[p];
        const int   ii = ki[i], ip = ki[p];
        const bool gt = (xi > xp) || (xi == xp && ii > ip);   // lex (x, idx): deterministic
        if (gt == up) { kx[i] = xp; kx[p] = xi; ki[i] = ip; ki[p] = ii; }
      }
      __syncthreads();
    }
  }
  for (int i = t; i < 4096; i += 1024) {
    const int j = ki[i];
    sp4[(size_t)b * 4096 + i] =
        make_float4(P[3 * j], P[3 * j + 1], P[3 * j + 2], __uint_as_float((unsigned)j));
  }
}

// ---------------- K1: x-slab KNN, 16 queries per INDEPENDENT wave ----------------
// R13 post-mortem: 8-way slab striding scanned ~15 slabs before threshold convergence,
// and 107KB LDS killed occupancy. Now: wave = 16 queries (lane = chunk c*16 + query q),
// strictly sequential outward scan (home, +1, -1, +2, ...) -> home slab bootstraps all
// thresholds; expected ~5-7 slabs. Top-16 as packed u64 key (d_bits<<16)|j: one u64
// compare per ladder level, lex (d, orig j) == numpy stable argsort; sentinel ~0ULL
// gives NaN threshold -> skip auto-disabled until 16 real entries. Skip margin
// (gap^2 > te*1.0001+1e-6, monotone outward) verified in R13. No stacks, no prunes.
#define PROC_SLAB(S)                                                                 \
  do {                                                                               \
    sl[l + (l >> 4)] = SP[(S) * 64 + l];      /* stride-17 pad: reads conflict-free */\
    asm volatile("s_waitcnt lgkmcnt(0)" ::: "memory");  /* intra-wave visibility */  \
    _Pragma("unroll")                                                                \
    for (int k = 0; k < 16; ++k) {                                                   \
      const float4 pc = sl[c * 17 + k];                                              \
      const float dx = qx - pc.x;                                                    \
      const float dy = qy - pc.y;                                                    \
      const float dz = qz - pc.z;                                                    \
      /* EXACT reference arithmetic: ((dx*dx+dy*dy)+dz*dz), f32, no FMA */           \
      const float d = __fadd_rn(__fadd_rn(__fmul_rn(dx, dx), __fmul_rn(dy, dy)),     \
                                __fmul_rn(dz, dz));                                  \
      const u64 key = ((u64)__float_as_uint(d) << 16) |                              \
                      (u64)(__float_as_uint(pc.w) & 0xFFFFu);                        \
      const bool ins = key < kl[15];                                                 \
      if (__any(ins)) {                                                              \
        const u64 vk = ins ? key : ~0ULL;                                            \
        bool cc[16];                                                                 \
        _Pragma("unroll")                                                            \
        for (int i = 0; i < 16; ++i) cc[i] = vk < kl[i];                             \
        _Pragma("unroll")                                                            \
        for (int i = 15; i >= 1; --i)                                                \
          kl[i] = cc[i] ? (cc[i - 1] ? kl[i - 1] : vk) : kl[i];                      \
        kl[0] = cc[0] ? vk : kl[0];                                                  \
      }                                                                              \
    }                                                                                \
  } while (0)

// te = min over the query's 4 c-lanes of d16 (hi bits of kl[15]); NaN while unfilled
#define TE_REFRESH()                                                                 \
  do {                                                                               \
    unsigned du = (unsigned)(kl[15] >> 16);                                          \
    unsigned o1 = (unsigned)__shfl_xor((int)du, 16); du = du < o1 ? du : o1;         \
    unsigned o2 = (unsigned)__shfl_xor((int)du, 32); du = du < o2 ? du : o2;         \
    te = __uint_as_float(du);                                                        \
  } while (0)

__global__ __launch_bounds__(256) void knn_kernel(const float4* __restrict__ sp4,
                                                  int* __restrict__ idx_out) {
  __shared__ float4 slab[4][68];       // per-wave slab, stride-17 float4 pad (4.3 KB)
  __shared__ u64    km[4][1088];       // per-wave merge lists [c*16+q]*17 + i (34.8 KB)

  const int t  = threadIdx.x;
  const int wv = t >> 6, l = t & 63;
  const int gw = blockIdx.x * 4 + wv;  // 1024 waves = 4 batches * 256 groups
  const int b  = gw >> 8, g = gw & 255;
  const float4* SP = sp4 + (size_t)b * 4096;
  const int q = l & 15;                // query within group
  const int c = l >> 4;                // candidate chunk 0..3 within slab

  const float4 mq = SP[g * 16 + q];
  const float qx = mq.x, qy = mq.y, qz = mq.z;

  u64 kl[16];
#pragma unroll
  for (int i = 0; i < 16; ++i) kl[i] = ~0ULL;

  float4* sl = slab[wv];
  float te;

  const int sh = g >> 2;               // home slab (group = quarter slab)
  PROC_SLAB(sh);
  int  sHi = sh + 1, sLo = sh - 1;
  bool hiOpen = sHi < 64, loOpen = sLo >= 0;

  while (hiOpen || loOpen) {
    if (hiOpen) {
      TE_REFRESH();
      const float gap = SP[sHi * 64].x - qx;          // >= 0 (sorted, slab above group)
      if (__all(__fmul_rn(gap, gap) > te * 1.0001f + 1e-6f)) hiOpen = false;
      else { PROC_SLAB(sHi); ++sHi; hiOpen = sHi < 64; }
    }
    if (loOpen) {
      TE_REFRESH();
      const float gap = qx - SP[sLo * 64 + 63].x;     // >= 0
      if (__all(__fmul_rn(gap, gap) > te * 1.0001f + 1e-6f)) loOpen = false;
      else { PROC_SLAB(sLo); --sLo; loOpen = sLo >= 0; }
    }
  }

  // ---- merge 4 chunk-lists per query (u64 lex compare), write original rows ----
  u64* kw = km[wv];
#pragma unroll
  for (int i = 0; i < 16; ++i) kw[l * 17 + i] = kl[i];   // banks 2l%32: 2-way, free
  asm volatile("s_waitcnt lgkmcnt(0)" ::: "memory");

  if (l < 16) {
    const int b0 = l * 17, b1 = (16 + l) * 17, b2 = (32 + l) * 17, b3 = (48 + l) * 17;
    int p0 = 0, p1 = 0, p2 = 0, p3 = 0;
    const unsigned oq = __float_as_uint(SP[g * 16 + l].w) & 0xFFFFu;
    int* op = idx_out + (((size_t)b * NPTS + oq) << 4);
    for (int r = 0; r < 16; ++r) {
      const u64 k0 = kw[b0 + p0];
      const u64 k1 = kw[b1 + p1];
      const u64 k2 = kw[b2 + p2];
      const u64 k3 = kw[b3 + p3];
      u64 bk = k0; int bw = 0;
      if (k1 < bk) { bk = k1; bw = 1; }
      if (k2 < bk) { bk = k2; bw = 2; }
      if (k3 < bk) { bk = k3; bw = 3; }
      op[r] = (int)(bk & 0xFFFFu);
      p0 += (bw == 0); p1 += (bw == 1); p2 += (bw == 2); p3 += (bw == 3);
    }
  }
}

// ---------------- K2: fused MLP, ALL of W2 in LDS (R12, unchanged) ----------
__global__ __launch_bounds__(512) void mlp_kernel(const float* __restrict__ pts,
                                                  const int* __restrict__ idx,
                                                  const float* __restrict__ W1,
                                                  const float* __restrict__ b1,
                                                  const _Float16* __restrict__ W2F,
                                                  const float* __restrict__ b2,
                                                  float* __restrict__ out) {
  __shared__ _Float16 sB[73728];       // 144 KiB: all of W2, fragment-major

  const int bid = blockIdx.x;          // 512 = 4 batches * 128 blocks
  const int b   = bid >> 7;
  const int t   = threadIdx.x;
  const int wv  = t >> 6;              // 8 waves
  const int q0  = ((bid & 127) << 5) + (wv << 2);   // 4 queries per wave
  const float* P = pts + (size_t)b * NPTS * 3;
  const int l   = t & 63;
  const int r   = l & 15;
  const int kg  = l >> 4;

#pragma unroll
  for (int i = 0; i < 18; ++i) {
    const int j = i * 512 + t;
    *(f16x8*)(sB + (size_t)j * 8) = *(const f16x8*)(W2F + (size_t)j * 8);
  }

  float f[4][6];
#pragma unroll
  for (int qi = 0; qi < 4; ++qi) {
    const int qq = q0 + qi;
    const int nb = idx[(((size_t)b * NPTS + qq) << 4) + r];
    const float ax = P[qq * 3 + 0], ay = P[qq * 3 + 1], az = P[qq * 3 + 2];
    f[qi][0] = P[nb * 3 + 0] - ax;
    f[qi][1] = P[nb * 3 + 1] - ay;
    f[qi][2] = P[nb * 3 + 2] - az;
    f[qi][3] = ax; f[qi][4] = ay; f[qi][5] = az;
  }

  f16x8 af[4][6];
#pragma unroll
  for (int kt = 0; kt < 6; ++kt) {
    const int h0 = kt * 32 + kg * 8;
    const f32x4 bb0 = *(const f32x4*)(b1 + h0);
    const f32x4 bb1 = *(const f32x4*)(b1 + h0 + 4);
    f32x4 w0[6], w1[6];
#pragma unroll
    for (int in = 0; in < 6; ++in) {
      w0[in] = *(const f32x4*)(W1 + in * HDIM + h0);
      w1[in] = *(const f32x4*)(W1 + in * HDIM + h0 + 4);
    }
#pragma unroll
    for (int qi = 0; qi < 4; ++qi) {
      f32x4 a0 = bb0, a1 = bb1;
#pragma unroll
      for (int in = 0; in < 6; ++in) {
        a0 += f[qi][in] * w0[in];
        a1 += f[qi][in] * w1[in];
      }
      f16x8 v;
#pragma unroll
      for (int j = 0; j < 4; ++j) {
        v[j]     = (_Float16)(a0[j] * __builtin_amdgcn_rcpf(1.0f + __expf(-a0[j])));
        v[j + 4] = (_Float16)(a1[j] * __builtin_amdgcn_rcpf(1.0f + __expf(-a1[j])));
      }
      af[qi][kt] = v;
    }
  }
  __syncthreads();

  const size_t orow = (size_t)b * NPTS + q0;
  const _Float16* bp = sB + (size_t)l * 8;

  for (int ct = 0; ct < 24; ++ct) {
    const int c = ct * 16 + r;
    f16x8 bfr[6];
#pragma unroll
    for (int kt = 0; kt < 6; ++kt)
      bfr[kt] = *(const f16x8*)(bp + (size_t)(ct * 6 + kt) * 512);

    f32x4 acc[4];
#pragma unroll
    for (int qi = 0; qi < 4; ++qi) acc[qi] = f32x4{0.f, 0.f, 0.f, 0.f};
#pragma unroll
    for (int kt = 0; kt < 6; ++kt)
#pragma unroll
      for (int qi = 0; qi < 4; ++qi)
        acc[qi] = __builtin_amdgcn_mfma_f32_16x16x32_f16(af[qi][kt], bfr[kt], acc[qi], 0, 0, 0);

    const float bb = b2[c];
#pragma unroll
    for (int qi = 0; qi < 4; ++qi) {
      float m = fmaxf(fmaxf(acc[qi][0], acc[qi][1]), fmaxf(acc[qi][2], acc[qi][3]));
      m = fmaxf(m, __shfl_xor(m, 16));
      m = fmaxf(m, __shfl_xor(m, 32));
      if (l < 16)
        out[(orow + qi) * CDIM + c] = m + bb;
    }
  }
}

extern "C" void kernel_launch(void* const* d_in, const int* in_sizes, int n_in,
                              void* d_out, int out_size, void* d_ws, size_t ws_size,
                              hipStream_t stream) {
  const float* point = (const float*)d_in[0];
  const float* W1    = (const float*)d_in[1];
  const float* b1    = (const float*)d_in[2];
  const float* W2    = (const float*)d_in[3];
  const float* b2    = (const float*)d_in[4];

  int*      idx_ws = (int*)d_ws;                                  // 1 MB
  float4*   sp4    = (float4*)((char*)d_ws + (1 << 20));          // 256 KB
  _Float16* W2F    = (_Float16*)((char*)d_ws + (1 << 20) + (256 << 10));  // 144 KB

  prep_w2<<<36, 256, 0, stream>>>(W2, W2F);
  sort_kernel<<<NBATCH, 1024, 0, stream>>>(point, sp4);
  knn_kernel<<<256, 256, 0, stream>>>(sp4, idx_ws);
  mlp_kernel<<<512, 512, 0, stream>>>(point, idx_ws, W1, b1, W2F, b2, (float*)d_out);
}

// Round 15
// 264.947 us; speedup vs baseline: 1.0673x; 1.0673x over previous
//
#include <hip/hip_runtime.h>

#define NPTS 4096
#define NBATCH 4
#define HDIM 192
#define CDIM 384
#define FINF 3.4e38f

typedef _Float16 f16x8 __attribute__((ext_vector_type(8)));
typedef float f32x4 __attribute__((ext_vector_type(4)));

// ---------------- K0: W2 [192][384] f32 -> fragment-major f16 chunks (R12, unchanged) --
__global__ __launch_bounds__(256) void prep_w2(const float* __restrict__ W2,
                                               _Float16* __restrict__ W2F) {
  const int j = blockIdx.x * 256 + threadIdx.x;   // 9216 chunks
  if (j < 9216) {
    const int lane = j & 63, r = lane & 15, kg = lane >> 4;
    const int kt = (j >> 6) % 6, ct = j / 384;
    const int c = ct * 16 + r, h0 = kt * 32 + kg * 8;
    f16x8 v;
#pragma unroll
    for (int e = 0; e < 8; ++e) v[e] = (_Float16)W2[(size_t)(h0 + e) * CDIM + c];
    *(f16x8*)(W2F + (size_t)j * 8) = v;
  }
}

// ---------------- KA: per-batch x-BUCKETING (replaces 49us bitonic sort) ----------------
// 64 linear x-bins: histogram -> prefix -> scatter. Within-bin order is atomic-arrival
// (nondeterministic) — harmless: selection is exact lex top-16 over ALL points and skip
// bounds are computed from actual bucket contents, so output is order-invariant.
__global__ __launch_bounds__(1024) void bucket_kernel(const float* __restrict__ pts,
                                                      float4* __restrict__ sp4,
                                                      float* __restrict__ bnds) {
  __shared__ float sx[4096];
  __shared__ float sxs[4096];
  __shared__ unsigned hist[64];
  __shared__ float rmn_s[16], rmx_s[16];
  __shared__ float gmin_s, ginvw_s;
  const int b = blockIdx.x;
  const float* P = pts + (size_t)b * NPTS * 3;
  const int t = threadIdx.x;

  float mn = FINF, mx = -FINF;
  for (int i = t; i < 4096; i += 1024) {
    const float x = P[3 * i];
    sx[i] = x;
    mn = fminf(mn, x);
    mx = fmaxf(mx, x);
  }
#pragma unroll
  for (int s = 32; s; s >>= 1) {
    mn = fminf(mn, __shfl_xor(mn, s));
    mx = fmaxf(mx, __shfl_xor(mx, s));
  }
  if ((t & 63) == 0) { rmn_s[t >> 6] = mn; rmx_s[t >> 6] = mx; }
  if (t < 64) hist[t] = 0;
  __syncthreads();
  if (t == 0) {
    float gmn = rmn_s[0], gmx = rmx_s[0];
    for (int i = 1; i < 16; ++i) { gmn = fminf(gmn, rmn_s[i]); gmx = fmaxf(gmx, rmx_s[i]); }
    gmin_s  = gmn;
    ginvw_s = (gmx > gmn) ? 64.0f / (gmx - gmn) : 0.0f;   // degenerate -> all bin 0
  }
  __syncthreads();
  const float gmn = gmin_s, ginvw = ginvw_s;
  for (int i = t; i < 4096; i += 1024) {
    int bn = (int)((sx[i] - gmn) * ginvw);
    bn = bn < 0 ? 0 : (bn > 63 ? 63 : bn);
    atomicAdd(&hist[bn], 1u);
  }
  __syncthreads();
  if (t == 0) {                       // exclusive prefix (becomes scatter offsets)
    unsigned run = 0;
    for (int i = 0; i < 64; ++i) { const unsigned c = hist[i]; hist[i] = run; run += c; }
  }
  __syncthreads();
  for (int i = t; i < 4096; i += 1024) {
    const float x = sx[i];
    int bn = (int)((x - gmn) * ginvw);
    bn = bn < 0 ? 0 : (bn > 63 ? 63 : bn);
    const unsigned pos = atomicAdd(&hist[bn], 1u);
    sp4[(size_t)b * 4096 + pos] =
        make_float4(x, P[3 * i + 1], P[3 * i + 2], __uint_as_float((unsigned)i));
    sxs[pos] = x;
  }
  __syncthreads();
  // per-256-range x bounds (16 ranges, one wave each)
  {
    const int rg = t >> 6, ln = t & 63;
    float rmn = FINF, rmx = -FINF;
    for (int k = ln; k < 256; k += 64) {
      const float v = sxs[rg * 256 + k];
      rmn = fminf(rmn, v);
      rmx = fmaxf(rmx, v);
    }
#pragma unroll
    for (int s = 32; s; s >>= 1) {
      rmn = fminf(rmn, __shfl_xor(rmn, s));
      rmx = fmaxf(rmx, __shfl_xor(rmx, s));
    }
    if (ln == 0) { bnds[b * 32 + rg * 2] = rmn; bnds[b * 32 + rg * 2 + 1] = rmx; }
  }
}

// ---------------- K1: KNN — R12 engine + bucketed chunks + static chunk-skip ------------
// 512 blocks x 512 thr; 32 bucketed-order queries/block; thread = (ql, cid); chunk =
// positions [cid*256,(cid+1)*256) of the bucketed array (x-coherent). Per-thread sticky
// fin when gap(chunk-bounds, qx)^2 > te*1.0001+1e-6 (sound: true d >= dx^2 > te >= d16);
// wave breaks on __all(fin). Lex (d, orig j) ladder/merge == numpy stable argsort
// (R13-verified). Shared sThr + stack-decoupled prune (R12-verified, 91us engine).
#define SCAP 15   // stacks 15KB; trigger at cnt>=7, burst <=8 -> max idx 14, safe

#define PRUNE()                                                                      \
  do {                                                                               \
    int mc = cnt;                                                                    \
    _Pragma("unroll")                                                                \
    for (int s_ = 32; s_; s_ >>= 1) { int o_ = __shfl_xor(mc, s_); mc = mc > o_ ? mc : o_; } \
    mc = __builtin_amdgcn_readfirstlane(mc);                                         \
    for (int e = 0; e < mc; ++e) {                                                   \
      const int s = sstk[sbase + e] & 4095;                                          \
      const float dx = qx - spx[s];                                                  \
      const float dy = qy - spy[s];                                                  \
      const float dz = qz - spz[s];                                                  \
      const float d = __fadd_rn(__fadd_rn(__fmul_rn(dx, dx), __fmul_rn(dy, dy)),     \
                                __fmul_rn(dz, dz));                                  \
      const bool act = (e < cnt);                                                    \
      const float    dd = act ? d : FINF;                                            \
      const unsigned jj = act ? spw[s] : 0xFFFFFFFFu;                                \
      bool cc[16];                                                                   \
      _Pragma("unroll")                                                              \
      for (int i = 0; i < 16; ++i)                                                   \
        cc[i] = (dd < dl[i]) || (dd == dl[i] && jj < il[i]);                         \
      _Pragma("unroll")                                                              \
      for (int i = 15; i >= 1; --i) {                                                \
        dl[i] = cc[i] ? (cc[i - 1] ? dl[i - 1] : dd) : dl[i];                        \
        il[i] = cc[i] ? (cc[i - 1] ? il[i - 1] : jj) : il[i];                        \
      }                                                                              \
      dl[0] = cc[0] ? dd : dl[0];                                                    \
      il[0] = cc[0] ? jj : il[0];                                                    \
    }                                                                                \
    cnt = 0;                                                                         \
    thr = dl[15];                                                                    \
    atomicMin(&sThrU[ql], __float_as_uint(thr));                                     \
  } while (0)

__global__ __launch_bounds__(512) void knn_kernel(const float4* __restrict__ sp4,
                                                  const float* __restrict__ bnds,
                                                  int* __restrict__ idx_out) {
  __shared__ float smem[16384];             // 64KB: spx,spy,spz,spw; later md+mi alias
  __shared__ unsigned short sstk[7680];     // 15KB stacks; later od+oj alias
  __shared__ unsigned sThrU[32];

  float*    spx = smem;
  float*    spy = smem + 4096;
  float*    spz = smem + 8192;
  unsigned* spw = (unsigned*)(smem + 12288);

  const int t  = threadIdx.x;
  const int b  = blockIdx.x >> 7;           // 128 blocks per batch
  const int g  = blockIdx.x & 127;          // query group (32 bucketed positions)
  const float4* SP = sp4 + (size_t)b * 4096;

  for (int i = t; i < 4096; i += 512) {
    const float4 v = SP[i];
    spx[i] = v.x; spy[i] = v.y; spz[i] = v.z;
    spw[i] = __float_as_uint(v.w);
  }
  if (t < 32) sThrU[t] = __float_as_uint(FINF);
  __syncthreads();

  const int ql    = t & 31;
  const int cid   = (t >> 5) & 15;
  const int cbase = cid << 8;
  const int qpos  = g * 32 + ql;
  const float qx = spx[qpos], qy = spy[qpos], qz = spz[qpos];
  const unsigned oq = spw[qpos];            // original query row (captured pre-alias)

  // static chunk gap^2 (bounds from bucket contents)
  const float cmin = bnds[b * 32 + cid * 2];
  const float cmax = bnds[b * 32 + cid * 2 + 1];
  const float gapc = fmaxf(fmaxf(cmin - qx, qx - cmax), 0.0f);
  const float g2   = __fmul_rn(gapc, gapc);

  float    dl[16];
  unsigned il[16];
#pragma unroll
  for (int i = 0; i < 16; ++i) { dl[i] = FINF; il[i] = 0xFFFFFFFFu; }
  float thr = FINF;
  int   cnt = 0;
  const int sbase = t * SCAP;
  bool fin = false;

  for (int jt = 0; jt < 256; jt += 8) {
    const unsigned tb = ((volatile unsigned*)sThrU)[ql];
    const float te = fminf(thr, __uint_as_float(tb));
    fin = fin || (g2 > te * 1.0001f + 1e-6f);     // sticky; te only shrinks
    if (__all(fin)) break;
    if (!fin) {
      const int jb = cbase + jt;
      const f32x4 x0 = *(const f32x4*)(spx + jb);
      const f32x4 x1 = *(const f32x4*)(spx + jb + 4);
      const f32x4 y0 = *(const f32x4*)(spy + jb);
      const f32x4 y1 = *(const f32x4*)(spy + jb + 4);
      const f32x4 z0 = *(const f32x4*)(spz + jb);
      const f32x4 z1 = *(const f32x4*)(spz + jb + 4);
#pragma unroll
      for (int u = 0; u < 8; ++u) {
        const float px = (u < 4) ? x0[u & 3] : x1[u & 3];
        const float py = (u < 4) ? y0[u & 3] : y1[u & 3];
        const float pz = (u < 4) ? z0[u & 3] : z1[u & 3];
        const float dx = qx - px;
        const float dy = qy - py;
        const float dz = qz - pz;
        // EXACT reference arithmetic: ((dx*dx+dy*dy)+dz*dz), f32, no FMA
        const float d = __fadd_rn(__fadd_rn(__fmul_rn(dx, dx), __fmul_rn(dy, dy)),
                                  __fmul_rn(dz, dz));
        if (d <= te) { sstk[sbase + cnt] = (unsigned short)(jb + u); ++cnt; }
      }
    }
    if (__any(cnt >= SCAP - 8)) PRUNE();
  }
  PRUNE();   // drain

  __syncthreads();   // points/stacks dead -> alias merge arrays

  float*          md = smem;                               // f32[32*257]
  unsigned short* mi = (unsigned short*)(smem + 8224);     // u16[32*257]
  {
    const int lbase = ql * 257 + cid * 16;
#pragma unroll
    for (int i = 0; i < 16; ++i) {
      md[lbase + i] = dl[i];
      mi[lbase + i] = (unsigned short)il[i];
    }
  }
  __syncthreads();

  // stage 1: 16 lists -> 4 per query (128 thr), lex (d, orig j)
  float*          od = (float*)sstk;                           // f32[32*65]
  unsigned short* oj = (unsigned short*)((char*)sstk + 8320);  // u16[32*65]
  if (t < 128) {
    const int mq = t >> 2, grp = t & 3;
    const int base = mq * 257 + grp * 64;
    int p0 = 0, p1 = 0, p2 = 0, p3 = 0;
    const int ob = mq * 65 + grp * 16;
    for (int r = 0; r < 16; ++r) {
      const float d0 = md[base + p0];
      const float d1 = md[base + 16 + p1];
      const float d2 = md[base + 32 + p2];
      const float d3 = md[base + 48 + p3];
      const unsigned short j0 = mi[base + p0];
      const unsigned short j1 = mi[base + 16 + p1];
      const unsigned short j2 = mi[base + 32 + p2];
      const unsigned short j3 = mi[base + 48 + p3];
      float bd = d0; unsigned short bj = j0; int bw = 0;
      if (d1 < bd || (d1 == bd && j1 < bj)) { bd = d1; bj = j1; bw = 1; }
      if (d2 < bd || (d2 == bd && j2 < bj)) { bd = d2; bj = j2; bw = 2; }
      if (d3 < bd || (d3 == bd && j3 < bj)) { bd = d3; bj = j3; bw = 3; }
      od[ob + r] = bd;
      oj[ob + r] = bj;
      p0 += (bw == 0); p1 += (bw == 1); p2 += (bw == 2); p3 += (bw == 3);
    }
  }
  __syncthreads();

  // stage 2: 4 lists -> 1 (32 thr), write to ORIGINAL query row
  if (t < 32) {
    const int base = t * 65;
    int p0 = 0, p1 = 0, p2 = 0, p3 = 0;
    int* op = idx_out + (((size_t)b * NPTS + oq) << 4);   // thread t has ql==t -> own oq
    for (int r = 0; r < 16; ++r) {
      const float d0 = od[base + p0];
      const float d1 = od[base + 16 + p1];
      const float d2 = od[base + 32 + p2];
      const float d3 = od[base + 48 + p3];
      const unsigned short j0 = oj[base + p0];
      const unsigned short j1 = oj[base + 16 + p1];
      const unsigned short j2 = oj[base + 32 + p2];
      const unsigned short j3 = oj[base + 48 + p3];
      float bd = d0; unsigned short bj = j0; int bw = 0;
      if (d1 < bd || (d1 == bd && j1 < bj)) { bd = d1; bj = j1; bw = 1; }
      if (d2 < bd || (d2 == bd && j2 < bj)) { bd = d2; bj = j2; bw = 2; }
      if (d3 < bd || (d3 == bd && j3 < bj)) { bd = d3; bj = j3; bw = 3; }
      op[r] = (int)bj;
      p0 += (bw == 0); p1 += (bw == 1); p2 += (bw == 2); p3 += (bw == 3);
    }
  }
}

// ---------------- K2: fused MLP, ALL of W2 in LDS (R12, unchanged) ----------
__global__ __launch_bounds__(512) void mlp_kernel(const float* __restrict__ pts,
                                                  const int* __restrict__ idx,
                                                  const float* __restrict__ W1,
                                                  const float* __restrict__ b1,
                                                  const _Float16* __restrict__ W2F,
                                                  const float* __restrict__ b2,
                                                  float* __restrict__ out) {
  __shared__ _Float16 sB[73728];       // 144 KiB: all of W2, fragment-major

  const int bid = blockIdx.x;          // 512 = 4 batches * 128 blocks
  const int b   = bid >> 7;
  const int t   = threadIdx.x;
  const int wv  = t >> 6;              // 8 waves
  const int q0  = ((bid & 127) << 5) + (wv << 2);   // 4 queries per wave
  const float* P = pts + (size_t)b * NPTS * 3;
  const int l   = t & 63;
  const int r   = l & 15;
  const int kg  = l >> 4;

#pragma unroll
  for (int i = 0; i < 18; ++i) {
    const int j = i * 512 + t;
    *(f16x8*)(sB + (size_t)j * 8) = *(const f16x8*)(W2F + (size_t)j * 8);
  }

  float f[4][6];
#pragma unroll
  for (int qi = 0; qi < 4; ++qi) {
    const int qq = q0 + qi;
    const int nb = idx[(((size_t)b * NPTS + qq) << 4) + r];
    const float ax = P[qq * 3 + 0], ay = P[qq * 3 + 1], az = P[qq * 3 + 2];
    f[qi][0] = P[nb * 3 + 0] - ax;
    f[qi][1] = P[nb * 3 + 1] - ay;
    f[qi][2] = P[nb * 3 + 2] - az;
    f[qi][3] = ax; f[qi][4] = ay; f[qi][5] = az;
  }

  f16x8 af[4][6];
#pragma unroll
  for (int kt = 0; kt < 6; ++kt) {
    const int h0 = kt * 32 + kg * 8;
    const f32x4 bb0 = *(const f32x4*)(b1 + h0);
    const f32x4 bb1 = *(const f32x4*)(b1 + h0 + 4);
    f32x4 w0[6], w1[6];
#pragma unroll
    for (int in = 0; in < 6; ++in) {
      w0[in] = *(const f32x4*)(W1 + in * HDIM + h0);
      w1[in] = *(const f32x4*)(W1 + in * HDIM + h0 + 4);
    }
#pragma unroll
    for (int qi = 0; qi < 4; ++qi) {
      f32x4 a0 = bb0, a1 = bb1;
#pragma unroll
      for (int in = 0; in < 6; ++in) {
        a0 += f[qi][in] * w0[in];
        a1 += f[qi][in] * w1[in];
      }
      f16x8 v;
#pragma unroll
      for (int j = 0; j < 4; ++j) {
        v[j]     = (_Float16)(a0[j] * __builtin_amdgcn_rcpf(1.0f + __expf(-a0[j])));
        v[j + 4] = (_Float16)(a1[j] * __builtin_amdgcn_rcpf(1.0f + __expf(-a1[j])));
      }
      af[qi][kt] = v;
    }
  }
  __syncthreads();

  const size_t orow = (size_t)b * NPTS + q0;
  const _Float16* bp = sB + (size_t)l * 8;

  for (int ct = 0; ct < 24; ++ct) {
    const int c = ct * 16 + r;
    f16x8 bfr[6];
#pragma unroll
    for (int kt = 0; kt < 6; ++kt)
      bfr[kt] = *(const f16x8*)(bp + (size_t)(ct * 6 + kt) * 512);

    f32x4 acc[4];
#pragma unroll
    for (int qi = 0; qi < 4; ++qi) acc[qi] = f32x4{0.f, 0.f, 0.f, 0.f};
#pragma unroll
    for (int kt = 0; kt < 6; ++kt)
#pragma unroll
      for (int qi = 0; qi < 4; ++qi)
        acc[qi] = __builtin_amdgcn_mfma_f32_16x16x32_f16(af[qi][kt], bfr[kt], acc[qi], 0, 0, 0);

    const float bb = b2[c];
#pragma unroll
    for (int qi = 0; qi < 4; ++qi) {
      float m = fmaxf(fmaxf(acc[qi][0], acc[qi][1]), fmaxf(acc[qi][2], acc[qi][3]));
      m = fmaxf(m, __shfl_xor(m, 16));
      m = fmaxf(m, __shfl_xor(m, 32));
      if (l < 16)
        out[(orow + qi) * CDIM + c] = m + bb;
    }
  }
}

extern "C" void kernel_launch(void* const* d_in, const int* in_sizes, int n_in,
                              void* d_out, int out_size, void* d_ws, size_t ws_size,
                              hipStream_t stream) {
  const float* point = (const float*)d_in[0];
  const float* W1    = (const float*)d_in[1];
  const float* b1    = (const float*)d_in[2];
  const float* W2    = (const float*)d_in[3];
  const float* b2    = (const float*)d_in[4];

  int*      idx_ws = (int*)d_ws;                                        // 1 MB
  float4*   sp4    = (float4*)((char*)d_ws + (1 << 20));                // 256 KB
  _Float16* W2F    = (_Float16*)((char*)d_ws + (1 << 20) + (256 << 10));// 144 KB
  float*    bnds   = (float*)((char*)d_ws + (1 << 20) + (512 << 10));   // 512 B

  prep_w2<<<36, 256, 0, stream>>>(W2, W2F);
  bucket_kernel<<<NBATCH, 1024, 0, stream>>>(point, sp4, bnds);
  knn_kernel<<<512, 512, 0, stream>>>(sp4, bnds, idx_ws);
  mlp_kernel<<<512, 512, 0, stream>>>(point, idx_ws, W1, b1, W2F, b2, (float*)d_out);
}